// Round 1
// baseline (4797.318 us; speedup 1.0000x reference)
//
#include <hip/hip_runtime.h>
#include <cmath>

#define NH   12
#define DH   64
#define AHD  768
#define BB   8
#define SLQ  1024
#define SLK  1024
#define DIM  768

// ---------------- Projection GEMM: Y[M=8192, N=768] = X @ W^T + bias ----------------
// W is [N, K] row-major; Y[m,n] = sum_k X[m,k] * W[n,k] + bias[n]
__global__ __launch_bounds__(256) void proj_kernel(
    const float* __restrict__ X, const float* __restrict__ W,
    const float* __restrict__ bias, float* __restrict__ Y) {
  __shared__ float As[16][128];
  __shared__ float Bs[16][128];
  const int t  = threadIdx.x;
  const int bm = blockIdx.x * 128;
  const int bn = blockIdx.y * 128;
  const int lr = t >> 1;          // 0..127 (row within tile for loads)
  const int lc = (t & 1) * 8;     // 0 or 8 (k-offset for loads)
  const int tm = (t >> 4) * 8;    // output row group
  const int tn = (t & 15) * 8;    // output col group

  float acc[8][8];
#pragma unroll
  for (int i = 0; i < 8; ++i)
#pragma unroll
    for (int j = 0; j < 8; ++j) acc[i][j] = 0.f;

  for (int k0 = 0; k0 < DIM; k0 += 16) {
    float4 x0 = *(const float4*)&X[(size_t)(bm + lr) * DIM + k0 + lc];
    float4 x1 = *(const float4*)&X[(size_t)(bm + lr) * DIM + k0 + lc + 4];
    float4 w0 = *(const float4*)&W[(size_t)(bn + lr) * DIM + k0 + lc];
    float4 w1 = *(const float4*)&W[(size_t)(bn + lr) * DIM + k0 + lc + 4];
    As[lc + 0][lr] = x0.x; As[lc + 1][lr] = x0.y; As[lc + 2][lr] = x0.z; As[lc + 3][lr] = x0.w;
    As[lc + 4][lr] = x1.x; As[lc + 5][lr] = x1.y; As[lc + 6][lr] = x1.z; As[lc + 7][lr] = x1.w;
    Bs[lc + 0][lr] = w0.x; Bs[lc + 1][lr] = w0.y; Bs[lc + 2][lr] = w0.z; Bs[lc + 3][lr] = w0.w;
    Bs[lc + 4][lr] = w1.x; Bs[lc + 5][lr] = w1.y; Bs[lc + 6][lr] = w1.z; Bs[lc + 7][lr] = w1.w;
    __syncthreads();
#pragma unroll
    for (int kk = 0; kk < 16; ++kk) {
      float a[8], bb[8];
      *(float4*)&a[0]  = *(const float4*)&As[kk][tm];
      *(float4*)&a[4]  = *(const float4*)&As[kk][tm + 4];
      *(float4*)&bb[0] = *(const float4*)&Bs[kk][tn];
      *(float4*)&bb[4] = *(const float4*)&Bs[kk][tn + 4];
#pragma unroll
      for (int i = 0; i < 8; ++i)
#pragma unroll
        for (int j = 0; j < 8; ++j) acc[i][j] = fmaf(a[i], bb[j], acc[i][j]);
    }
    __syncthreads();
  }

  float bv[8];
  *(float4*)&bv[0] = *(const float4*)&bias[bn + tn];
  *(float4*)&bv[4] = *(const float4*)&bias[bn + tn + 4];
#pragma unroll
  for (int i = 0; i < 8; ++i) {
    float4 r0 = make_float4(acc[i][0] + bv[0], acc[i][1] + bv[1],
                            acc[i][2] + bv[2], acc[i][3] + bv[3]);
    float4 r1 = make_float4(acc[i][4] + bv[4], acc[i][5] + bv[5],
                            acc[i][6] + bv[6], acc[i][7] + bv[7]);
    *(float4*)&Y[(size_t)(bm + tm + i) * DIM + bn + tn]     = r0;
    *(float4*)&Y[(size_t)(bm + tm + i) * DIM + bn + tn + 4] = r1;
  }
}

// ---------------- Attention stage (used for both stage 1 and stage 2) ----------------
// One wave handles one q-row of one (h,b). Layouts are merged-head [B, L, AHD]:
// element (b, i, h*64+d). Scores masked by mask[b, ki]; optional p write ([H,B,LQ,LK]);
// optional tanh on output.
__global__ __launch_bounds__(256) void attn_kernel(
    const float* __restrict__ Qm, const float* __restrict__ Km,
    const float* __restrict__ Vm, const int* __restrict__ mask,
    float* __restrict__ Oout, float* __restrict__ Pout, const int applyTanh) {
  __shared__ float qsh[4][64];
  __shared__ float psh[4][1024];
  const int lane = threadIdx.x & 63;
  const int w    = threadIdx.x >> 6;
  const int qi   = blockIdx.x * 4 + w;
  const int b    = blockIdx.y;
  const int h    = blockIdx.z;

  const size_t rowOff = ((size_t)b * SLQ + qi) * DIM + h * DH;
  qsh[w][lane] = Qm[rowOff + lane];
  __syncthreads();

  const float scale = 0.03608439182435161f;  // 1/sqrt(768)
  const float* Kb = Km + (size_t)b * SLK * DIM + h * DH;
  const int*   mb = mask + b * SLK;

  float s[16];
  float mx = -INFINITY;
  for (int t16 = 0; t16 < 16; ++t16) {
    const int ki = t16 * 64 + lane;
    if (mb[ki] == 1) {
      const float4* kp = (const float4*)(Kb + (size_t)ki * DIM);
      float acc = 0.f;
#pragma unroll
      for (int d = 0; d < 16; ++d) {
        float4 kv = kp[d];
        acc = fmaf(qsh[w][4 * d + 0], kv.x, acc);
        acc = fmaf(qsh[w][4 * d + 1], kv.y, acc);
        acc = fmaf(qsh[w][4 * d + 2], kv.z, acc);
        acc = fmaf(qsh[w][4 * d + 3], kv.w, acc);
      }
      s[t16] = acc * scale;
    } else {
      s[t16] = -INFINITY;
    }
    mx = fmaxf(mx, s[t16]);
  }
#pragma unroll
  for (int off = 32; off >= 1; off >>= 1) mx = fmaxf(mx, __shfl_xor(mx, off));

  float e[16];
  float sum = 0.f;
#pragma unroll
  for (int t16 = 0; t16 < 16; ++t16) {
    e[t16] = (s[t16] == -INFINITY) ? 0.f : __expf(s[t16] - mx);
    sum += e[t16];
  }
#pragma unroll
  for (int off = 32; off >= 1; off >>= 1) sum += __shfl_xor(sum, off);
  const float inv = 1.f / sum;

#pragma unroll
  for (int t16 = 0; t16 < 16; ++t16) psh[w][t16 * 64 + lane] = e[t16] * inv;
  if (Pout) {
    float* pb = Pout + ((size_t)(h * BB + b) * SLQ + qi) * SLK;
#pragma unroll
    for (int t16 = 0; t16 < 16; ++t16) pb[t16 * 64 + lane] = e[t16] * inv;
  }
  __syncthreads();

  // PV: lane owns output dim d = lane
  const float* vp = Vm + (size_t)b * SLK * DIM + h * DH + lane;
  float o = 0.f;
#pragma unroll 8
  for (int ki = 0; ki < SLK; ++ki) {
    o = fmaf(psh[w][ki], vp[(size_t)ki * DIM], o);
  }
  Oout[rowOff + lane] = applyTanh ? tanhf(o) : o;
}

extern "C" void kernel_launch(void* const* d_in, const int* in_sizes, int n_in,
                              void* d_out, int out_size, void* d_ws, size_t ws_size,
                              hipStream_t stream) {
  const float* query = (const float*)d_in[0];
  const float* key   = (const float*)d_in[1];
  const int*   qmask = (const int*)d_in[2];
  const int*   kmask = (const int*)d_in[3];
  const float* Wq = (const float*)d_in[4];
  const float* bq = (const float*)d_in[5];
  const float* Wk = (const float*)d_in[6];
  const float* bk = (const float*)d_in[7];
  const float* Wv = (const float*)d_in[8];
  const float* bv = (const float*)d_in[9];

  float* out   = (float*)d_out;
  const size_t bufElems = (size_t)BB * SLQ * AHD;  // 6,291,456
  float* p2out = out + bufElems;                   // [H,B,LQ,LK] region (402 MB)

  // Scratch: Q/K/V live in the p2 region of d_out (dead before stage 2 overwrites
  // it); O1 lives in d_ws (25 MB). Everything is fully rewritten every call.
  float* Qb = p2out;
  float* Kb = p2out + bufElems;
  float* Vb = p2out + 2 * bufElems;
  float* O1 = (float*)d_ws;

  dim3 pgrid(8192 / 128, DIM / 128);  // (64, 6)
  proj_kernel<<<pgrid, dim3(256), 0, stream>>>(query, Wq, bq, Qb);
  proj_kernel<<<pgrid, dim3(256), 0, stream>>>(key,   Wk, bk, Kb);
  proj_kernel<<<pgrid, dim3(256), 0, stream>>>(key,   Wv, bv, Vb);

  dim3 agrid(SLQ / 4, BB, NH);
  attn_kernel<<<agrid, dim3(256), 0, stream>>>(Qb, Kb, Vb, kmask, O1, (float*)nullptr, 0);
  attn_kernel<<<agrid, dim3(256), 0, stream>>>(O1, O1, O1, qmask, out, p2out, 1);
}

// Round 2
// 733.973 us; speedup vs baseline: 6.5361x; 6.5361x over previous
//
#include <hip/hip_runtime.h>
#include <cmath>

#define NH   12
#define DH   64
#define AHD  768
#define BB   8
#define SLQ  1024
#define SLK  1024
#define DIM  768
#define KPAD 72   // 64 + 8 pad: row stride 144B (8B-aligned, breaks bank-conflict stride)

typedef unsigned short u16;
typedef _Float16 f16x8 __attribute__((ext_vector_type(8)));
typedef float    f32x4 __attribute__((ext_vector_type(4)));

union F8 { f16x8 v; uint2 u2[2]; uint4 u4; u16 s[8]; };

__device__ inline u16 f2h(float f) {
  union { _Float16 h; u16 u; } c;
  c.h = (_Float16)f;
  return c.u;
}

// ---------------- Projection GEMM: Y[M=8192, N=768](f16) = X @ W^T + bias ----------------
__global__ __launch_bounds__(256) void proj_kernel(
    const float* __restrict__ X, const float* __restrict__ W,
    const float* __restrict__ bias, u16* __restrict__ Y) {
  __shared__ float As[16][128];
  __shared__ float Bs[16][128];
  const int t  = threadIdx.x;
  const int bm = blockIdx.x * 128;
  const int bn = blockIdx.y * 128;
  const int lr = t >> 1;
  const int lc = (t & 1) * 8;
  const int tm = (t >> 4) * 8;
  const int tn = (t & 15) * 8;

  float acc[8][8];
#pragma unroll
  for (int i = 0; i < 8; ++i)
#pragma unroll
    for (int j = 0; j < 8; ++j) acc[i][j] = 0.f;

  for (int k0 = 0; k0 < DIM; k0 += 16) {
    float4 x0 = *(const float4*)&X[(size_t)(bm + lr) * DIM + k0 + lc];
    float4 x1 = *(const float4*)&X[(size_t)(bm + lr) * DIM + k0 + lc + 4];
    float4 w0 = *(const float4*)&W[(size_t)(bn + lr) * DIM + k0 + lc];
    float4 w1 = *(const float4*)&W[(size_t)(bn + lr) * DIM + k0 + lc + 4];
    As[lc + 0][lr] = x0.x; As[lc + 1][lr] = x0.y; As[lc + 2][lr] = x0.z; As[lc + 3][lr] = x0.w;
    As[lc + 4][lr] = x1.x; As[lc + 5][lr] = x1.y; As[lc + 6][lr] = x1.z; As[lc + 7][lr] = x1.w;
    Bs[lc + 0][lr] = w0.x; Bs[lc + 1][lr] = w0.y; Bs[lc + 2][lr] = w0.z; Bs[lc + 3][lr] = w0.w;
    Bs[lc + 4][lr] = w1.x; Bs[lc + 5][lr] = w1.y; Bs[lc + 6][lr] = w1.z; Bs[lc + 7][lr] = w1.w;
    __syncthreads();
#pragma unroll
    for (int kk = 0; kk < 16; ++kk) {
      float a[8], bb[8];
      *(float4*)&a[0]  = *(const float4*)&As[kk][tm];
      *(float4*)&a[4]  = *(const float4*)&As[kk][tm + 4];
      *(float4*)&bb[0] = *(const float4*)&Bs[kk][tn];
      *(float4*)&bb[4] = *(const float4*)&Bs[kk][tn + 4];
#pragma unroll
      for (int i = 0; i < 8; ++i)
#pragma unroll
        for (int j = 0; j < 8; ++j) acc[i][j] = fmaf(a[i], bb[j], acc[i][j]);
    }
    __syncthreads();
  }

  float bv[8];
  *(float4*)&bv[0] = *(const float4*)&bias[bn + tn];
  *(float4*)&bv[4] = *(const float4*)&bias[bn + tn + 4];
#pragma unroll
  for (int i = 0; i < 8; ++i) {
    uint4 pk;
    pk.x = (unsigned)f2h(acc[i][0] + bv[0]) | ((unsigned)f2h(acc[i][1] + bv[1]) << 16);
    pk.y = (unsigned)f2h(acc[i][2] + bv[2]) | ((unsigned)f2h(acc[i][3] + bv[3]) << 16);
    pk.z = (unsigned)f2h(acc[i][4] + bv[4]) | ((unsigned)f2h(acc[i][5] + bv[5]) << 16);
    pk.w = (unsigned)f2h(acc[i][6] + bv[6]) | ((unsigned)f2h(acc[i][7] + bv[7]) << 16);
    *(uint4*)&Y[(size_t)(bm + tm + i) * DIM + bn + tn] = pk;
  }
}

// ---------------- MFMA attention (two-pass softmax), fp16 inputs, f32 accum ----------------
// Grid (LQ/64, B, H); 4 waves; wave w owns q rows [qr0, qr0+16).
// mfma_f32_16x16x32_f16 layouts:
//   A[16x32]: lane l -> row l&15, k = (l>>4)*8 + j
//   B[32x16]: lane l -> col l&15, k = (l>>4)*8 + j
//   C[16x16]: lane l -> col l&15, row = (l>>4)*4 + reg
__global__ __launch_bounds__(256) void attn_mfma(
    const u16* __restrict__ Qm, const u16* __restrict__ Km,
    const u16* __restrict__ Vm, const int* __restrict__ mask,
    u16* __restrict__ Obf, float* __restrict__ Of32,
    float* __restrict__ Pout) {
  __shared__ u16 Ks[64][KPAD];      // [key][d]
  __shared__ u16 Vt[64][KPAD];      // [d][key]  (transposed)
  __shared__ u16 Ps[4][16][KPAD];   // per wave: [qrow][key]

  const int t  = threadIdx.x;
  const int w  = t >> 6;
  const int l  = t & 63;
  const int b  = blockIdx.y;
  const int h  = blockIdx.z;
  const int qr0 = blockIdx.x * 64 + w * 16;

  const int lr = l & 15;   // A-row / B-col / C-col
  const int lg = l >> 4;   // lane group

  const float scale = 0.03608439182435161f;  // 1/sqrt(768)

  // Q fragments (2 K-steps of 32)
  f16x8 qa[2];
  {
    const u16* qp = Qm + ((size_t)(b * SLQ + qr0 + lr)) * AHD + h * DH + lg * 8;
    qa[0] = *(const f16x8*)qp;
    qa[1] = *(const f16x8*)(qp + 32);
  }

  const int skey = t >> 2;          // staging: key row (0..63)
  const int sseg = (t & 3) * 16;    // staging: d offset
  const size_t gBase = (size_t)b * SLK * AHD + h * DH + sseg;
  const int* mb = mask + b * SLK;

  float mrun[4] = {-1e30f, -1e30f, -1e30f, -1e30f};
  float lrun[4] = {0.f, 0.f, 0.f, 0.f};

  // ---------------- pass 1: row max + denom ----------------
  for (int kt = 0; kt < SLK / 64; ++kt) {
    const int k0 = kt * 64;
    __syncthreads();
    {
      const uint4* g = (const uint4*)(Km + gBase + (size_t)(k0 + skey) * AHD);
      uint4 g0 = g[0], g1 = g[1];
      uint2* dst = (uint2*)&Ks[skey][sseg];
      dst[0] = make_uint2(g0.x, g0.y); dst[1] = make_uint2(g0.z, g0.w);
      dst[2] = make_uint2(g1.x, g1.y); dst[3] = make_uint2(g1.z, g1.w);
    }
    __syncthreads();

    f32x4 sacc[4];
#pragma unroll
    for (int ct = 0; ct < 4; ++ct) {
      sacc[ct] = (f32x4){0.f, 0.f, 0.f, 0.f};
#pragma unroll
      for (int ks = 0; ks < 2; ++ks) {
        F8 kb;
        const uint2* kp = (const uint2*)&Ks[ct * 16 + lr][ks * 32 + lg * 8];
        kb.u2[0] = kp[0]; kb.u2[1] = kp[1];
        sacc[ct] = __builtin_amdgcn_mfma_f32_16x16x32_f16(qa[ks], kb.v, sacc[ct], 0, 0, 0);
      }
    }

    int mk[4];
#pragma unroll
    for (int ct = 0; ct < 4; ++ct) mk[ct] = mb[k0 + ct * 16 + lr];

#pragma unroll
    for (int r = 0; r < 4; ++r) {
      float sv[4];
      float tmax = -1e30f;
#pragma unroll
      for (int ct = 0; ct < 4; ++ct) {
        sv[ct] = (mk[ct] == 1) ? sacc[ct][r] * scale : -1e30f;
        tmax = fmaxf(tmax, sv[ct]);
      }
#pragma unroll
      for (int off = 8; off >= 1; off >>= 1) tmax = fmaxf(tmax, __shfl_xor(tmax, off));
      const float mnew = fmaxf(mrun[r], tmax);
      float ssum = 0.f;
#pragma unroll
      for (int ct = 0; ct < 4; ++ct)
        ssum += (sv[ct] > -1e29f) ? __expf(sv[ct] - mnew) : 0.f;
#pragma unroll
      for (int off = 8; off >= 1; off >>= 1) ssum += __shfl_xor(ssum, off);
      lrun[r] = lrun[r] * __expf(mrun[r] - mnew) + ssum;
      mrun[r] = mnew;
    }
  }

  float invl[4];
#pragma unroll
  for (int r = 0; r < 4; ++r) invl[r] = 1.f / lrun[r];

  // ---------------- pass 2: p (normalized), optional P write, PV ----------------
  f32x4 oacc[4];
#pragma unroll
  for (int dt = 0; dt < 4; ++dt) oacc[dt] = (f32x4){0.f, 0.f, 0.f, 0.f};

  for (int kt = 0; kt < SLK / 64; ++kt) {
    const int k0 = kt * 64;
    __syncthreads();
    {
      const uint4* g = (const uint4*)(Km + gBase + (size_t)(k0 + skey) * AHD);
      uint4 g0 = g[0], g1 = g[1];
      uint2* dst = (uint2*)&Ks[skey][sseg];
      dst[0] = make_uint2(g0.x, g0.y); dst[1] = make_uint2(g0.z, g0.w);
      dst[2] = make_uint2(g1.x, g1.y); dst[3] = make_uint2(g1.z, g1.w);
    }
    {
      const uint4* g = (const uint4*)(Vm + gBase + (size_t)(k0 + skey) * AHD);
      F8 t0, t1;
      t0.u4 = g[0]; t1.u4 = g[1];
#pragma unroll
      for (int j = 0; j < 8; ++j) Vt[sseg + j][skey] = t0.s[j];
#pragma unroll
      for (int j = 0; j < 8; ++j) Vt[sseg + 8 + j][skey] = t1.s[j];
    }
    __syncthreads();

    f32x4 sacc[4];
#pragma unroll
    for (int ct = 0; ct < 4; ++ct) {
      sacc[ct] = (f32x4){0.f, 0.f, 0.f, 0.f};
#pragma unroll
      for (int ks = 0; ks < 2; ++ks) {
        F8 kb;
        const uint2* kp = (const uint2*)&Ks[ct * 16 + lr][ks * 32 + lg * 8];
        kb.u2[0] = kp[0]; kb.u2[1] = kp[1];
        sacc[ct] = __builtin_amdgcn_mfma_f32_16x16x32_f16(qa[ks], kb.v, sacc[ct], 0, 0, 0);
      }
    }

    int mk[4];
#pragma unroll
    for (int ct = 0; ct < 4; ++ct) mk[ct] = mb[k0 + ct * 16 + lr];

#pragma unroll
    for (int ct = 0; ct < 4; ++ct) {
      float p[4];
#pragma unroll
      for (int r = 0; r < 4; ++r) {
        const float s = sacc[ct][r] * scale;
        p[r] = (mk[ct] == 1) ? __expf(s - mrun[r]) * invl[r] : 0.f;
      }
      if (Pout) {
#pragma unroll
        for (int r = 0; r < 4; ++r)
          Pout[((size_t)(h * BB + b) * SLQ + qr0 + lg * 4 + r) * SLK + k0 + ct * 16 + lr] = p[r];
      }
#pragma unroll
      for (int r = 0; r < 4; ++r) Ps[w][lg * 4 + r][ct * 16 + lr] = f2h(p[r]);
    }
    __syncthreads();

    f16x8 pa[2];
#pragma unroll
    for (int ks = 0; ks < 2; ++ks) {
      F8 u;
      const uint2* pp = (const uint2*)&Ps[w][lr][ks * 32 + lg * 8];
      u.u2[0] = pp[0]; u.u2[1] = pp[1];
      pa[ks] = u.v;
    }
#pragma unroll
    for (int dt = 0; dt < 4; ++dt) {
#pragma unroll
      for (int ks = 0; ks < 2; ++ks) {
        F8 u;
        const uint2* vp = (const uint2*)&Vt[dt * 16 + lr][ks * 32 + lg * 8];
        u.u2[0] = vp[0]; u.u2[1] = vp[1];
        oacc[dt] = __builtin_amdgcn_mfma_f32_16x16x32_f16(pa[ks], u.v, oacc[dt], 0, 0, 0);
      }
    }
  }

  // ---------------- output ----------------
  const size_t obase = ((size_t)(b * SLQ + qr0 + lg * 4)) * AHD + h * DH;
  if (Obf) {
#pragma unroll
    for (int dt = 0; dt < 4; ++dt)
#pragma unroll
      for (int r = 0; r < 4; ++r)
        Obf[obase + (size_t)r * AHD + dt * 16 + lr] = f2h(oacc[dt][r]);
  }
  if (Of32) {
#pragma unroll
    for (int dt = 0; dt < 4; ++dt)
#pragma unroll
      for (int r = 0; r < 4; ++r)
        Of32[obase + (size_t)r * AHD + dt * 16 + lr] = tanhf(oacc[dt][r]);
  }
}

extern "C" void kernel_launch(void* const* d_in, const int* in_sizes, int n_in,
                              void* d_out, int out_size, void* d_ws, size_t ws_size,
                              hipStream_t stream) {
  const float* query = (const float*)d_in[0];
  const float* key   = (const float*)d_in[1];
  const int*   qmask = (const int*)d_in[2];
  const int*   kmask = (const int*)d_in[3];
  const float* Wq = (const float*)d_in[4];
  const float* bq = (const float*)d_in[5];
  const float* Wk = (const float*)d_in[6];
  const float* bk = (const float*)d_in[7];
  const float* Wv = (const float*)d_in[8];
  const float* bv = (const float*)d_in[9];

  float* out = (float*)d_out;
  const size_t bufE = (size_t)BB * SLQ * AHD;   // 6,291,456
  float* p2out = out + bufE;                    // [H,B,LQ,LK] region (402 MB)

  // fp16 scratch: Q/K/V inside the (not-yet-written) p2 region; O1 in d_ws.
  u16* Qb = (u16*)p2out;
  u16* Kb = Qb + bufE;
  u16* Vb = Kb + bufE;
  u16* O1 = (u16*)d_ws;

  dim3 pgrid(8192 / 128, DIM / 128);
  proj_kernel<<<pgrid, dim3(256), 0, stream>>>(query, Wq, bq, Qb);
  proj_kernel<<<pgrid, dim3(256), 0, stream>>>(key,   Wk, bk, Kb);
  proj_kernel<<<pgrid, dim3(256), 0, stream>>>(key,   Wv, bv, Vb);

  dim3 agrid(SLQ / 64, BB, NH);
  attn_mfma<<<agrid, dim3(256), 0, stream>>>(Qb, Kb, Vb, kmask, O1, nullptr, nullptr);
  attn_mfma<<<agrid, dim3(256), 0, stream>>>(O1, O1, O1, qmask, nullptr, out, p2out);
}

// Round 3
// 362.463 us; speedup vs baseline: 13.2353x; 2.0250x over previous
//
#include <hip/hip_runtime.h>
#include <cmath>

#define NH   12
#define DH   64
#define AHD  768
#define BB   8
#define SLQ  1024
#define SLK  1024
#define DIM  768

typedef unsigned short u16;
typedef _Float16 f16x8 __attribute__((ext_vector_type(8)));
typedef float    f32x4 __attribute__((ext_vector_type(4)));

union F8 { f16x8 v; uint4 u4; u16 s[8]; };

__device__ inline u16 f2h(float f) {
  union { _Float16 h; u16 u; } c;
  c.h = (_Float16)f;
  return c.u;
}
__device__ inline f16x8 ldsF8(const u16* p) { F8 u; u.u4 = *(const uint4*)p; return u.v; }

// ---------------- fp16-MFMA projection: Y[8192,768] = X(f32) @ W(f32)^T + bias ----------------
// Tile 128x128, BK=32, 4 waves each computing 64x64. LDS chunk-XOR swizzle (j ^= row&3).
// Optional transposed output Yt[b, n, l] (for V / stage-2's V = O1^T).
__global__ __launch_bounds__(256) void proj_mfma(
    const float* __restrict__ X, const float* __restrict__ W,
    const float* __restrict__ bias, u16* __restrict__ Y, u16* __restrict__ Yt) {
  __shared__ __align__(16) u16 As[128 * 32];
  __shared__ __align__(16) u16 Bs[128 * 32];
  const int t  = threadIdx.x;
  const int w  = t >> 6, l = t & 63;
  const int lr = l & 15, lg = l >> 4;
  const int wr = w >> 1, wc = w & 1;
  const int bm = blockIdx.x * 128, bn = blockIdx.y * 128;

  const int srow = t >> 1;        // 0..127
  const int sjp  = (t & 1) * 2;   // chunk pair base (chunks of 8 elems)

  f32x4 acc[4][4];
#pragma unroll
  for (int i = 0; i < 4; ++i)
#pragma unroll
    for (int j = 0; j < 4; ++j) acc[i][j] = (f32x4){0.f, 0.f, 0.f, 0.f};

  for (int k0 = 0; k0 < DIM; k0 += 32) {
    __syncthreads();
    {
      const float* src = X + (size_t)(bm + srow) * DIM + k0 + sjp * 8;
      float4 f0 = ((const float4*)src)[0];
      float4 f1 = ((const float4*)src)[1];
      float4 f2 = ((const float4*)src)[2];
      float4 f3 = ((const float4*)src)[3];
      F8 c0, c1;
      c0.v = (f16x8){(_Float16)f0.x, (_Float16)f0.y, (_Float16)f0.z, (_Float16)f0.w,
                     (_Float16)f1.x, (_Float16)f1.y, (_Float16)f1.z, (_Float16)f1.w};
      c1.v = (f16x8){(_Float16)f2.x, (_Float16)f2.y, (_Float16)f2.z, (_Float16)f2.w,
                     (_Float16)f3.x, (_Float16)f3.y, (_Float16)f3.z, (_Float16)f3.w};
      *(uint4*)&As[srow * 32 + ((sjp)     ^ (srow & 3)) * 8] = c0.u4;
      *(uint4*)&As[srow * 32 + ((sjp + 1) ^ (srow & 3)) * 8] = c1.u4;
    }
    {
      const float* src = W + (size_t)(bn + srow) * DIM + k0 + sjp * 8;
      float4 f0 = ((const float4*)src)[0];
      float4 f1 = ((const float4*)src)[1];
      float4 f2 = ((const float4*)src)[2];
      float4 f3 = ((const float4*)src)[3];
      F8 c0, c1;
      c0.v = (f16x8){(_Float16)f0.x, (_Float16)f0.y, (_Float16)f0.z, (_Float16)f0.w,
                     (_Float16)f1.x, (_Float16)f1.y, (_Float16)f1.z, (_Float16)f1.w};
      c1.v = (f16x8){(_Float16)f2.x, (_Float16)f2.y, (_Float16)f2.z, (_Float16)f2.w,
                     (_Float16)f3.x, (_Float16)f3.y, (_Float16)f3.z, (_Float16)f3.w};
      *(uint4*)&Bs[srow * 32 + ((sjp)     ^ (srow & 3)) * 8] = c0.u4;
      *(uint4*)&Bs[srow * 32 + ((sjp + 1) ^ (srow & 3)) * 8] = c1.u4;
    }
    __syncthreads();

    f16x8 af[4], bf[4];
#pragma unroll
    for (int mt = 0; mt < 4; ++mt) {
      const int row = wr * 64 + mt * 16 + lr;
      af[mt] = ldsF8(&As[row * 32 + (lg ^ (row & 3)) * 8]);
    }
#pragma unroll
    for (int nt = 0; nt < 4; ++nt) {
      const int row = wc * 64 + nt * 16 + lr;
      bf[nt] = ldsF8(&Bs[row * 32 + (lg ^ (row & 3)) * 8]);
    }
#pragma unroll
    for (int mt = 0; mt < 4; ++mt)
#pragma unroll
      for (int nt = 0; nt < 4; ++nt)
        acc[mt][nt] = __builtin_amdgcn_mfma_f32_16x16x32_f16(af[mt], bf[nt], acc[mt][nt], 0, 0, 0);
  }

  float bvn[4];
#pragma unroll
  for (int nt = 0; nt < 4; ++nt) bvn[nt] = bias[bn + wc * 64 + nt * 16 + lr];

#pragma unroll
  for (int mt = 0; mt < 4; ++mt) {
    const int m0 = bm + wr * 64 + mt * 16 + lg * 4;
#pragma unroll
    for (int nt = 0; nt < 4; ++nt) {
      const int n = bn + wc * 64 + nt * 16 + lr;
#pragma unroll
      for (int r = 0; r < 4; ++r) {
        const float val = acc[mt][nt][r] + bvn[nt];
        const u16 hv = f2h(val);
        const int m = m0 + r;
        if (Y)  Y[(size_t)m * DIM + n] = hv;
        if (Yt) {
          const int b2 = m >> 10, ll = m & 1023;
          Yt[((size_t)b2 * DIM + n) * SLK + ll] = hv;
        }
      }
    }
  }
}

// ---------------- MFMA attention, no-max softmax (scores provably < ~1) ----------------
// MODE 0: stage 1, single pass — unnormalized PV + denom accumulate, scale at end.
//         Writes O fp16 (O16) and O^T fp16 (O16t).
// MODE 1: stage 2, two passes (p2 must be written normalized). Writes Pout f32 + tanh(out) f32.
// LDS: K[64key][64d], V^T[64d][64key], P[w][16q][64key], all chunk-XOR swizzled (j ^= row&7).
template <int MODE>
__global__ __launch_bounds__(256) void attn_mfma(
    const u16* __restrict__ Qm, const u16* __restrict__ Km,
    const u16* __restrict__ Vt, const int* __restrict__ mask,
    u16* __restrict__ O16, u16* __restrict__ O16t,
    float* __restrict__ Of32, float* __restrict__ Pout) {
  __shared__ __align__(16) u16 Ks[64 * 64];
  __shared__ __align__(16) u16 Vs[64 * 64];
  __shared__ __align__(16) u16 Ps[4][16 * 64];

  const int t  = threadIdx.x;
  const int w  = t >> 6, l = t & 63;
  const int lr = l & 15, lg = l >> 4;
  const int b  = blockIdx.y;
  const int h  = blockIdx.z;
  const int qr0 = blockIdx.x * 64 + w * 16;

  const float scale = 0.03608439182435161f;  // 1/sqrt(768)

  f16x8 qa[2];
  {
    const u16* qp = Qm + ((size_t)(b * SLQ + qr0 + lr)) * AHD + h * DH + lg * 8;
    qa[0] = *(const f16x8*)qp;
    qa[1] = *(const f16x8*)(qp + 32);
  }

  const int skey = t >> 2;         // staged row (key for K, d for V^T)
  const int sj   = (t & 3) * 2;    // chunk pair
  const u16* Kg = Km + (size_t)b * SLK * AHD + h * DH;
  const u16* Vg = Vt + ((size_t)b * AHD + h * DH) * SLK;
  const int* mb = mask + b * SLK;

  float lrun[4] = {0.f, 0.f, 0.f, 0.f};
  f32x4 oacc[4];
#pragma unroll
  for (int dt = 0; dt < 4; ++dt) oacc[dt] = (f32x4){0.f, 0.f, 0.f, 0.f};

  const int NPASS = (MODE == 1) ? 2 : 1;
  float invl[4] = {1.f, 1.f, 1.f, 1.f};

  for (int pass = 0; pass < NPASS; ++pass) {
    const bool last = (pass == NPASS - 1);
    if (MODE == 1 && last) {
#pragma unroll
      for (int r = 0; r < 4; ++r) invl[r] = 1.f / lrun[r];
    }
    for (int kt = 0; kt < SLK / 64; ++kt) {
      const int k0 = kt * 64;
      __syncthreads();
      {
        const u16* src = Kg + (size_t)(k0 + skey) * AHD + sj * 8;
        uint4 g0 = ((const uint4*)src)[0];
        uint4 g1 = ((const uint4*)src)[1];
        *(uint4*)&Ks[skey * 64 + ((sj)     ^ (skey & 7)) * 8] = g0;
        *(uint4*)&Ks[skey * 64 + ((sj + 1) ^ (skey & 7)) * 8] = g1;
      }
      if (last) {
        const u16* src = Vg + (size_t)skey * SLK + k0 + sj * 8;
        uint4 g0 = ((const uint4*)src)[0];
        uint4 g1 = ((const uint4*)src)[1];
        *(uint4*)&Vs[skey * 64 + ((sj)     ^ (skey & 7)) * 8] = g0;
        *(uint4*)&Vs[skey * 64 + ((sj + 1) ^ (skey & 7)) * 8] = g1;
      }
      __syncthreads();

      f32x4 sacc[4];
#pragma unroll
      for (int ct = 0; ct < 4; ++ct) {
        sacc[ct] = (f32x4){0.f, 0.f, 0.f, 0.f};
        const int key = ct * 16 + lr;
#pragma unroll
        for (int ks = 0; ks < 2; ++ks) {
          f16x8 kb = ldsF8(&Ks[key * 64 + ((ks * 4 + lg) ^ (key & 7)) * 8]);
          sacc[ct] = __builtin_amdgcn_mfma_f32_16x16x32_f16(qa[ks], kb, sacc[ct], 0, 0, 0);
        }
      }

      int mk[4];
#pragma unroll
      for (int ct = 0; ct < 4; ++ct) mk[ct] = mb[k0 + ct * 16 + lr];

      float p[4][4];
#pragma unroll
      for (int ct = 0; ct < 4; ++ct)
#pragma unroll
        for (int r = 0; r < 4; ++r)
          p[ct][r] = (mk[ct] == 1) ? __expf(sacc[ct][r] * scale) : 0.f;

      if (!(MODE == 1 && last)) {
#pragma unroll
        for (int r = 0; r < 4; ++r) {
          float rs = p[0][r] + p[1][r] + p[2][r] + p[3][r];
#pragma unroll
          for (int off = 8; off >= 1; off >>= 1) rs += __shfl_xor(rs, off);
          lrun[r] += rs;
        }
      }

      if (last) {
        if (MODE == 1) {
#pragma unroll
          for (int ct = 0; ct < 4; ++ct)
#pragma unroll
            for (int r = 0; r < 4; ++r) p[ct][r] *= invl[r];
#pragma unroll
          for (int ct = 0; ct < 4; ++ct)
#pragma unroll
            for (int r = 0; r < 4; ++r)
              Pout[((size_t)(h * BB + b) * SLQ + qr0 + lg * 4 + r) * SLK + k0 + ct * 16 + lr] = p[ct][r];
        }
        // P -> per-wave LDS (fp16), XOR-swizzled
#pragma unroll
        for (int ct = 0; ct < 4; ++ct) {
          const int jj = ct * 2 + (lr >> 3);
#pragma unroll
          for (int r = 0; r < 4; ++r) {
            const int q = lg * 4 + r;
            Ps[w][q * 64 + (jj ^ (q & 7)) * 8 + (lr & 7)] = f2h(p[ct][r]);
          }
        }
        __asm__ volatile("s_waitcnt lgkmcnt(0)" ::: "memory");

        f16x8 pa[2];
#pragma unroll
        for (int ks = 0; ks < 2; ++ks)
          pa[ks] = ldsF8(&Ps[w][lr * 64 + ((ks * 4 + lg) ^ (lr & 7)) * 8]);
#pragma unroll
        for (int dt = 0; dt < 4; ++dt) {
          const int d = dt * 16 + lr;
#pragma unroll
          for (int ks = 0; ks < 2; ++ks) {
            f16x8 vb = ldsF8(&Vs[d * 64 + ((ks * 4 + lg) ^ (d & 7)) * 8]);
            oacc[dt] = __builtin_amdgcn_mfma_f32_16x16x32_f16(pa[ks], vb, oacc[dt], 0, 0, 0);
          }
        }
      }
    }
  }

  if (MODE == 0) {
#pragma unroll
    for (int r = 0; r < 4; ++r) invl[r] = 1.f / lrun[r];
#pragma unroll
    for (int dt = 0; dt < 4; ++dt) {
      const int d = h * DH + dt * 16 + lr;
#pragma unroll
      for (int r = 0; r < 4; ++r) {
        const int q = qr0 + lg * 4 + r;
        const u16 hv = f2h(oacc[dt][r] * invl[r]);
        O16[((size_t)(b * SLQ + q)) * AHD + d] = hv;
        O16t[((size_t)b * AHD + d) * SLQ + q] = hv;
      }
    }
  } else {
#pragma unroll
    for (int dt = 0; dt < 4; ++dt) {
      const int d = h * DH + dt * 16 + lr;
#pragma unroll
      for (int r = 0; r < 4; ++r) {
        const int q = qr0 + lg * 4 + r;
        Of32[((size_t)(b * SLQ + q)) * AHD + d] = tanhf(oacc[dt][r]);
      }
    }
  }
}

extern "C" void kernel_launch(void* const* d_in, const int* in_sizes, int n_in,
                              void* d_out, int out_size, void* d_ws, size_t ws_size,
                              hipStream_t stream) {
  const float* query = (const float*)d_in[0];
  const float* key   = (const float*)d_in[1];
  const int*   qmask = (const int*)d_in[2];
  const int*   kmask = (const int*)d_in[3];
  const float* Wq = (const float*)d_in[4];
  const float* bq = (const float*)d_in[5];
  const float* Wk = (const float*)d_in[6];
  const float* bk = (const float*)d_in[7];
  const float* Wv = (const float*)d_in[8];
  const float* bv = (const float*)d_in[9];

  float* out = (float*)d_out;
  const size_t bufE = (size_t)BB * SLQ * AHD;  // 6,291,456
  float* p2out = out + bufE;                   // [H,B,LQ,LK] region (402 MB)

  // fp16 scratch in the not-yet-written p2 region (stage-1 only; stage-2 never reads it):
  u16* Qb  = (u16*)p2out;
  u16* Kb  = Qb + bufE;
  u16* Vtb = Kb + bufE;        // V^T [B,768,1024]
  // O1 / O1^T in d_ws (stage-2 reads these while writing p2):
  u16* O1  = (u16*)d_ws;
  u16* O1t = O1 + bufE;

  dim3 pgrid(8192 / 128, DIM / 128);  // (64, 6)
  proj_mfma<<<pgrid, dim3(256), 0, stream>>>(query, Wq, bq, Qb, nullptr);
  proj_mfma<<<pgrid, dim3(256), 0, stream>>>(key,   Wk, bk, Kb, nullptr);
  proj_mfma<<<pgrid, dim3(256), 0, stream>>>(key,   Wv, bv, nullptr, Vtb);

  dim3 agrid(SLQ / 64, BB, NH);
  attn_mfma<0><<<agrid, dim3(256), 0, stream>>>(Qb, Kb, Vtb, kmask, O1, O1t, nullptr, nullptr);
  attn_mfma<1><<<agrid, dim3(256), 0, stream>>>(O1, O1, O1t, qmask, nullptr, nullptr, out, p2out);
}

// Round 5
// 315.388 us; speedup vs baseline: 15.2109x; 1.1493x over previous
//
#include <hip/hip_runtime.h>
#include <cmath>

#define NH   12
#define DH   64
#define AHD  768
#define BB   8
#define SLQ  1024
#define SLK  1024
#define DIM  768

typedef unsigned short u16;
typedef _Float16 f16x8 __attribute__((ext_vector_type(8)));
typedef __fp16   fp16x2 __attribute__((ext_vector_type(2)));
typedef float    f32x4 __attribute__((ext_vector_type(4)));

union F8 { f16x8 v; uint4 u4; u16 s[8]; };

__device__ inline u16 f2h(float f) {
  union { _Float16 h; u16 u; } c;
  c.h = (_Float16)f;
  return c.u;
}
__device__ inline f16x8 ldsF8(const u16* p) { F8 u; u.u4 = *(const uint4*)p; return u.v; }
__device__ inline unsigned pk2(float a, float b) {
  union { fp16x2 h; unsigned u; } c;
  c.h = __builtin_amdgcn_cvt_pkrtz(a, b);
  return c.u;
}

// ---------------- fp16-MFMA projection: Y[8192,768] = X(f32) @ W(f32)^T + bias ----------------
__global__ __launch_bounds__(256) void proj_mfma(
    const float* __restrict__ X, const float* __restrict__ W,
    const float* __restrict__ bias, u16* __restrict__ Y, u16* __restrict__ Yt) {
  __shared__ __align__(16) u16 As[128 * 32];
  __shared__ __align__(16) u16 Bs[128 * 32];
  const int t  = threadIdx.x;
  const int w  = t >> 6, l = t & 63;
  const int lr = l & 15, lg = l >> 4;
  const int wr = w >> 1, wc = w & 1;
  const int bm = blockIdx.x * 128, bn = blockIdx.y * 128;

  const int srow = t >> 1;
  const int sjp  = (t & 1) * 2;

  f32x4 acc[4][4];
#pragma unroll
  for (int i = 0; i < 4; ++i)
#pragma unroll
    for (int j = 0; j < 4; ++j) acc[i][j] = (f32x4){0.f, 0.f, 0.f, 0.f};

  for (int k0 = 0; k0 < DIM; k0 += 32) {
    __syncthreads();
    {
      const float* src = X + (size_t)(bm + srow) * DIM + k0 + sjp * 8;
      float4 f0 = ((const float4*)src)[0];
      float4 f1 = ((const float4*)src)[1];
      float4 f2 = ((const float4*)src)[2];
      float4 f3 = ((const float4*)src)[3];
      F8 c0, c1;
      c0.v = (f16x8){(_Float16)f0.x, (_Float16)f0.y, (_Float16)f0.z, (_Float16)f0.w,
                     (_Float16)f1.x, (_Float16)f1.y, (_Float16)f1.z, (_Float16)f1.w};
      c1.v = (f16x8){(_Float16)f2.x, (_Float16)f2.y, (_Float16)f2.z, (_Float16)f2.w,
                     (_Float16)f3.x, (_Float16)f3.y, (_Float16)f3.z, (_Float16)f3.w};
      *(uint4*)&As[srow * 32 + ((sjp)     ^ (srow & 3)) * 8] = c0.u4;
      *(uint4*)&As[srow * 32 + ((sjp + 1) ^ (srow & 3)) * 8] = c1.u4;
    }
    {
      const float* src = W + (size_t)(bn + srow) * DIM + k0 + sjp * 8;
      float4 f0 = ((const float4*)src)[0];
      float4 f1 = ((const float4*)src)[1];
      float4 f2 = ((const float4*)src)[2];
      float4 f3 = ((const float4*)src)[3];
      F8 c0, c1;
      c0.v = (f16x8){(_Float16)f0.x, (_Float16)f0.y, (_Float16)f0.z, (_Float16)f0.w,
                     (_Float16)f1.x, (_Float16)f1.y, (_Float16)f1.z, (_Float16)f1.w};
      c1.v = (f16x8){(_Float16)f2.x, (_Float16)f2.y, (_Float16)f2.z, (_Float16)f2.w,
                     (_Float16)f3.x, (_Float16)f3.y, (_Float16)f3.z, (_Float16)f3.w};
      *(uint4*)&Bs[srow * 32 + ((sjp)     ^ (srow & 3)) * 8] = c0.u4;
      *(uint4*)&Bs[srow * 32 + ((sjp + 1) ^ (srow & 3)) * 8] = c1.u4;
    }
    __syncthreads();

    f16x8 af[4], bf[4];
#pragma unroll
    for (int mt = 0; mt < 4; ++mt) {
      const int row = wr * 64 + mt * 16 + lr;
      af[mt] = ldsF8(&As[row * 32 + (lg ^ (row & 3)) * 8]);
    }
#pragma unroll
    for (int nt = 0; nt < 4; ++nt) {
      const int row = wc * 64 + nt * 16 + lr;
      bf[nt] = ldsF8(&Bs[row * 32 + (lg ^ (row & 3)) * 8]);
    }
#pragma unroll
    for (int mt = 0; mt < 4; ++mt)
#pragma unroll
      for (int nt = 0; nt < 4; ++nt)
        acc[mt][nt] = __builtin_amdgcn_mfma_f32_16x16x32_f16(af[mt], bf[nt], acc[mt][nt], 0, 0, 0);
  }

  float bvn[4];
#pragma unroll
  for (int nt = 0; nt < 4; ++nt) bvn[nt] = bias[bn + wc * 64 + nt * 16 + lr];

#pragma unroll
  for (int mt = 0; mt < 4; ++mt) {
    const int m0 = bm + wr * 64 + mt * 16 + lg * 4;
#pragma unroll
    for (int nt = 0; nt < 4; ++nt) {
      const int n = bn + wc * 64 + nt * 16 + lr;
#pragma unroll
      for (int r = 0; r < 4; ++r) {
        const float val = acc[mt][nt][r] + bvn[nt];
        const u16 hv = f2h(val);
        const int m = m0 + r;
        if (Y)  Y[(size_t)m * DIM + n] = hv;
        if (Yt) {
          const int b2 = m >> 10, ll = m & 1023;
          Yt[((size_t)b2 * DIM + n) * SLK + ll] = hv;
        }
      }
    }
  }
}

// ---------------- swapped-QK^T MFMA attention pass ----------------
// S^T tile via mfma(K_frag, Q_frag): C col = q (lr), row = k-in-16 (lg*4+r).
// DO_PV: stage P (packed b64) -> LDS, PV via mfma(P_frag, Vt_frag).
// NORM_P: multiply p by invl (per-lane, q=lr) and write f32 float4 to Pout.
// ACC_L: accumulate row-sums into lrun (shfl 16,32).
template <bool DO_PV, bool NORM_P, bool ACC_L>
__device__ __forceinline__ void attn_pass(
    const u16* __restrict__ Kg, const u16* __restrict__ Vg,
    const float* __restrict__ Msf,
    u16* __restrict__ Ks0, u16* __restrict__ Ks1,
    u16* __restrict__ Vs0, u16* __restrict__ Vs1,
    u16* __restrict__ Psw,
    const f16x8 (&qa)[2][2], const int lr, const int lg,
    float (&lrun)[2], const float (&invl)[2], f32x4 (&oacc)[2][4],
    float* __restrict__ Pout, const size_t poutRow0,
    const int skey, const int sj) {
  const float scale = 0.03608439182435161f;  // 1/sqrt(768)

  // prologue: stage tile 0
  {
    const u16* s = Kg + (size_t)skey * AHD + sj * 8;
    uint4 a = ((const uint4*)s)[0], b2 = ((const uint4*)s)[1];
    *(uint4*)&Ks0[skey * 64 + ((sj)     ^ (skey & 7)) * 8] = a;
    *(uint4*)&Ks0[skey * 64 + ((sj + 1) ^ (skey & 7)) * 8] = b2;
    if (DO_PV) {
      const u16* sv = Vg + (size_t)skey * SLK + sj * 8;
      uint4 va = ((const uint4*)sv)[0], vb = ((const uint4*)sv)[1];
      *(uint4*)&Vs0[skey * 64 + ((sj)     ^ (skey & 7)) * 8] = va;
      *(uint4*)&Vs0[skey * 64 + ((sj + 1) ^ (skey & 7)) * 8] = vb;
    }
  }
  __syncthreads();

#pragma unroll 2
  for (int kt = 0; kt < SLK / 64; ++kt) {
    const int k0 = kt * 64;
    u16* Kc = (kt & 1) ? Ks1 : Ks0;
    u16* Kn = (kt & 1) ? Ks0 : Ks1;
    u16* Vc = (kt & 1) ? Vs1 : Vs0;
    u16* Vn = (kt & 1) ? Vs0 : Vs1;
    const bool more = (kt < SLK / 64 - 1);

    // T14: issue next-tile loads now, write to LDS after compute
    uint4 ka = {}, kb2 = {}, va = {}, vb = {};
    if (more) {
      const u16* s = Kg + (size_t)(k0 + 64 + skey) * AHD + sj * 8;
      ka = ((const uint4*)s)[0]; kb2 = ((const uint4*)s)[1];
      if (DO_PV) {
        const u16* sv = Vg + (size_t)skey * SLK + (k0 + 64) + sj * 8;
        va = ((const uint4*)sv)[0]; vb = ((const uint4*)sv)[1];
      }
    }

    // QK^T (swapped): 16 MFMA
    f32x4 sacc[2][4];
#pragma unroll
    for (int mt = 0; mt < 2; ++mt)
#pragma unroll
      for (int ct = 0; ct < 4; ++ct) sacc[mt][ct] = (f32x4){0.f, 0.f, 0.f, 0.f};
#pragma unroll
    for (int ct = 0; ct < 4; ++ct) {
      const int krow = ct * 16 + lr;
      f16x8 kf0 = ldsF8(&Kc[krow * 64 + ((lg)     ^ (krow & 7)) * 8]);
      f16x8 kf1 = ldsF8(&Kc[krow * 64 + ((4 + lg) ^ (krow & 7)) * 8]);
      sacc[0][ct] = __builtin_amdgcn_mfma_f32_16x16x32_f16(kf0, qa[0][0], sacc[0][ct], 0, 0, 0);
      sacc[0][ct] = __builtin_amdgcn_mfma_f32_16x16x32_f16(kf1, qa[0][1], sacc[0][ct], 0, 0, 0);
      sacc[1][ct] = __builtin_amdgcn_mfma_f32_16x16x32_f16(kf0, qa[1][0], sacc[1][ct], 0, 0, 0);
      sacc[1][ct] = __builtin_amdgcn_mfma_f32_16x16x32_f16(kf1, qa[1][1], sacc[1][ct], 0, 0, 0);
    }

    // softmax numerators (p overwrites sacc); mask multiplicative from LDS
    float ps[2] = {0.f, 0.f};
#pragma unroll
    for (int ct = 0; ct < 4; ++ct) {
      const float4 mm = *(const float4*)&Msf[k0 + ct * 16 + lg * 4];
      const float m4[4] = {mm.x, mm.y, mm.z, mm.w};
#pragma unroll
      for (int mt = 0; mt < 2; ++mt)
#pragma unroll
        for (int r = 0; r < 4; ++r) {
          float p = __expf(sacc[mt][ct][r] * scale) * m4[r];
          if (NORM_P) p *= invl[mt];
          sacc[mt][ct][r] = p;
          if (ACC_L) ps[mt] += p;
        }
    }
    if (ACC_L) {
#pragma unroll
      for (int mt = 0; mt < 2; ++mt) {
        float s = ps[mt];
        s += __shfl_xor(s, 16);
        s += __shfl_xor(s, 32);
        lrun[mt] += s;
      }
    }

    if (NORM_P) {
      // p2 write: contiguous float4 along k per (mt,ct)
#pragma unroll
      for (int mt = 0; mt < 2; ++mt)
#pragma unroll
        for (int ct = 0; ct < 4; ++ct) {
          float4 pv = make_float4(sacc[mt][ct][0], sacc[mt][ct][1], sacc[mt][ct][2], sacc[mt][ct][3]);
          *(float4*)&Pout[(poutRow0 + mt * 16 + lr) * (size_t)SLK + k0 + ct * 16 + lg * 4] = pv;
        }
    }

    if (DO_PV) {
      // packed P -> LDS: 8x ds_write_b64
#pragma unroll
      for (int mt = 0; mt < 2; ++mt) {
        const int prow = mt * 16 + lr;
#pragma unroll
        for (int ct = 0; ct < 4; ++ct) {
          uint2 w2;
          w2.x = pk2(sacc[mt][ct][0], sacc[mt][ct][1]);
          w2.y = pk2(sacc[mt][ct][2], sacc[mt][ct][3]);
          *(uint2*)&Psw[prow * 64 + (((ct * 2 + (lg >> 1)) ^ (prow & 7)) * 8) + (lg & 1) * 4] = w2;
        }
      }
      __asm__ volatile("s_waitcnt lgkmcnt(0)" ::: "memory");
      __builtin_amdgcn_sched_barrier(0);

      f16x8 pa[2][2];
#pragma unroll
      for (int mt = 0; mt < 2; ++mt) {
        const int prow = mt * 16 + lr;
        pa[mt][0] = ldsF8(&Psw[prow * 64 + ((lg)     ^ (prow & 7)) * 8]);
        pa[mt][1] = ldsF8(&Psw[prow * 64 + ((4 + lg) ^ (prow & 7)) * 8]);
      }
#pragma unroll
      for (int dt = 0; dt < 4; ++dt) {
        const int vrow = dt * 16 + lr;
        f16x8 vf0 = ldsF8(&Vc[vrow * 64 + ((lg)     ^ (vrow & 7)) * 8]);
        f16x8 vf1 = ldsF8(&Vc[vrow * 64 + ((4 + lg) ^ (vrow & 7)) * 8]);
        oacc[0][dt] = __builtin_amdgcn_mfma_f32_16x16x32_f16(pa[0][0], vf0, oacc[0][dt], 0, 0, 0);
        oacc[0][dt] = __builtin_amdgcn_mfma_f32_16x16x32_f16(pa[0][1], vf1, oacc[0][dt], 0, 0, 0);
        oacc[1][dt] = __builtin_amdgcn_mfma_f32_16x16x32_f16(pa[1][0], vf0, oacc[1][dt], 0, 0, 0);
        oacc[1][dt] = __builtin_amdgcn_mfma_f32_16x16x32_f16(pa[1][1], vf1, oacc[1][dt], 0, 0, 0);
      }
    }

    // late LDS write of prefetched tile
    if (more) {
      *(uint4*)&Kn[skey * 64 + ((sj)     ^ (skey & 7)) * 8] = ka;
      *(uint4*)&Kn[skey * 64 + ((sj + 1) ^ (skey & 7)) * 8] = kb2;
      if (DO_PV) {
        *(uint4*)&Vn[skey * 64 + ((sj)     ^ (skey & 7)) * 8] = va;
        *(uint4*)&Vn[skey * 64 + ((sj + 1) ^ (skey & 7)) * 8] = vb;
      }
    }
    __syncthreads();
  }
}

// MODE 0: stage 1 — single pass, unnormalized PV + denom, writes O fp16 + O^T fp16.
// MODE 1: stage 2 — pass1 (denoms), pass2 (normalized p2 f32 + PV), writes tanh f32.
template <int MODE>
__global__ __launch_bounds__(256) void attn_mfma(
    const u16* __restrict__ Qm, const u16* __restrict__ Km,
    const u16* __restrict__ Vt, const int* __restrict__ mask,
    u16* __restrict__ O16, u16* __restrict__ O16t,
    float* __restrict__ Of32, float* __restrict__ Pout) {
  __shared__ __align__(16) u16 Ks[2][64 * 64];
  __shared__ __align__(16) u16 Vs[2][64 * 64];
  __shared__ __align__(16) u16 Ps[4][32 * 64];
  __shared__ __align__(16) float Msf[SLK];

  const int t  = threadIdx.x;
  const int w  = t >> 6, l = t & 63;
  const int lr = l & 15, lg = l >> 4;
  const int b  = blockIdx.y, h = blockIdx.z;
  const int qr0 = blockIdx.x * 128 + w * 32;

  // mask -> LDS as float 0/1 (visible after attn_pass's prologue barrier)
  {
    const int4 mi = ((const int4*)(mask + (size_t)b * SLK))[t];
    *(float4*)&Msf[t * 4] = make_float4(mi.x == 1 ? 1.f : 0.f, mi.y == 1 ? 1.f : 0.f,
                                        mi.z == 1 ? 1.f : 0.f, mi.w == 1 ? 1.f : 0.f);
  }

  // Q fragments (held across passes)
  f16x8 qa[2][2];
#pragma unroll
  for (int mt = 0; mt < 2; ++mt) {
    const u16* qp = Qm + (size_t)(b * SLQ + qr0 + mt * 16 + lr) * AHD + h * DH + lg * 8;
    qa[mt][0] = *(const f16x8*)qp;
    qa[mt][1] = *(const f16x8*)(qp + 32);
  }

  const u16* Kg = Km + (size_t)b * SLK * AHD + h * DH;
  const u16* Vg = Vt + ((size_t)b * AHD + h * DH) * SLK;
  const size_t poutRow0 = ((size_t)(h * BB + b)) * SLQ + qr0;
  const int skey = t >> 2, sj = (t & 3) * 2;

  float lrun[2] = {0.f, 0.f};
  float invl[2] = {1.f, 1.f};
  f32x4 oacc[2][4];
#pragma unroll
  for (int mt = 0; mt < 2; ++mt)
#pragma unroll
    for (int dt = 0; dt < 4; ++dt) oacc[mt][dt] = (f32x4){0.f, 0.f, 0.f, 0.f};

  if (MODE == 0) {
    attn_pass<true, false, true>(Kg, Vg, Msf, Ks[0], Ks[1], Vs[0], Vs[1], Ps[w],
                                 qa, lr, lg, lrun, invl, oacc, nullptr, 0, skey, sj);
#pragma unroll
    for (int mt = 0; mt < 2; ++mt) invl[mt] = 1.f / lrun[mt];
#pragma unroll
    for (int mt = 0; mt < 2; ++mt) {
      float iv[4];
#pragma unroll
      for (int r = 0; r < 4; ++r) iv[r] = __shfl(invl[mt], lg * 4 + r);
#pragma unroll
      for (int dt = 0; dt < 4; ++dt) {
        const int d = h * DH + dt * 16 + lr;
#pragma unroll
        for (int r = 0; r < 4; ++r) {
          const int q = qr0 + mt * 16 + lg * 4 + r;
          const u16 hv = f2h(oacc[mt][dt][r] * iv[r]);
          O16[(size_t)(b * SLQ + q) * AHD + d] = hv;
          O16t[((size_t)b * AHD + d) * SLQ + q] = hv;
        }
      }
    }
  } else {
    attn_pass<false, false, true>(Kg, Vg, Msf, Ks[0], Ks[1], Vs[0], Vs[1], Ps[w],
                                  qa, lr, lg, lrun, invl, oacc, nullptr, 0, skey, sj);
#pragma unroll
    for (int mt = 0; mt < 2; ++mt) invl[mt] = 1.f / lrun[mt];
    attn_pass<true, true, false>(Kg, Vg, Msf, Ks[0], Ks[1], Vs[0], Vs[1], Ps[w],
                                 qa, lr, lg, lrun, invl, oacc, Pout, poutRow0, skey, sj);
#pragma unroll
    for (int mt = 0; mt < 2; ++mt)
#pragma unroll
      for (int dt = 0; dt < 4; ++dt) {
        const int d = h * DH + dt * 16 + lr;
#pragma unroll
        for (int r = 0; r < 4; ++r) {
          const int q = qr0 + mt * 16 + lg * 4 + r;
          Of32[(size_t)(b * SLQ + q) * AHD + d] = tanhf(oacc[mt][dt][r]);
        }
      }
  }
}

extern "C" void kernel_launch(void* const* d_in, const int* in_sizes, int n_in,
                              void* d_out, int out_size, void* d_ws, size_t ws_size,
                              hipStream_t stream) {
  const float* query = (const float*)d_in[0];
  const float* key   = (const float*)d_in[1];
  const int*   qmask = (const int*)d_in[2];
  const int*   kmask = (const int*)d_in[3];
  const float* Wq = (const float*)d_in[4];
  const float* bq = (const float*)d_in[5];
  const float* Wk = (const float*)d_in[6];
  const float* bk = (const float*)d_in[7];
  const float* Wv = (const float*)d_in[8];
  const float* bv = (const float*)d_in[9];

  float* out = (float*)d_out;
  const size_t bufE = (size_t)BB * SLQ * AHD;  // 6,291,456
  float* p2out = out + bufE;                   // [H,B,LQ,LK] region (402 MB)

  // fp16 scratch in the not-yet-written p2 region (dead before stage-2 writes p2):
  u16* Qb  = (u16*)p2out;
  u16* Kb  = Qb + bufE;
  u16* Vtb = Kb + bufE;        // V^T [B,768,1024]
  // O1 / O1^T in d_ws (read by stage 2 while p2 is written):
  u16* O1  = (u16*)d_ws;
  u16* O1t = O1 + bufE;

  dim3 pgrid(8192 / 128, DIM / 128);  // (64, 6)
  proj_mfma<<<pgrid, dim3(256), 0, stream>>>(query, Wq, bq, Qb, nullptr);
  proj_mfma<<<pgrid, dim3(256), 0, stream>>>(key,   Wk, bk, Kb, nullptr);
  proj_mfma<<<pgrid, dim3(256), 0, stream>>>(key,   Wv, bv, nullptr, Vtb);

  dim3 agrid(SLQ / 128, BB, NH);  // (8, 8, 12) = 768 blocks, 3/CU
  attn_mfma<0><<<agrid, dim3(256), 0, stream>>>(Qb, Kb, Vtb, kmask, O1, O1t, nullptr, nullptr);
  attn_mfma<1><<<agrid, dim3(256), 0, stream>>>(O1, O1, O1t, qmask, nullptr, nullptr, out, p2out);
}

// Round 6
// 287.392 us; speedup vs baseline: 16.6926x; 1.0974x over previous
//
#include <hip/hip_runtime.h>
#include <cmath>

#define NH   12
#define DH   64
#define AHD  768
#define BB   8
#define SLQ  1024
#define SLK  1024
#define DIM  768

typedef unsigned short u16;
typedef _Float16 f16x8 __attribute__((ext_vector_type(8)));
typedef __fp16   fp16x2 __attribute__((ext_vector_type(2)));
typedef float    f32x4 __attribute__((ext_vector_type(4)));

union F8 { f16x8 v; uint4 u4; u16 s[8]; };

__device__ inline u16 f2h(float f) {
  union { _Float16 h; u16 u; } c;
  c.h = (_Float16)f;
  return c.u;
}
__device__ inline f16x8 ldsF8(const u16* p) { F8 u; u.u4 = *(const uint4*)p; return u.v; }
__device__ inline unsigned pk2(float a, float b) {
  union { fp16x2 h; unsigned u; } c;
  c.h = __builtin_amdgcn_cvt_pkrtz(a, b);
  return c.u;
}

// ---------------- one-shot f32 -> fp16 conversion (inputs + weights) ----------------
__global__ __launch_bounds__(256) void cvt_f16(
    const float* __restrict__ q, const float* __restrict__ k,
    const float* __restrict__ wq, const float* __restrict__ wk, const float* __restrict__ wv,
    u16* __restrict__ q16, u16* __restrict__ k16,
    u16* __restrict__ wq16, u16* __restrict__ wk16, u16* __restrict__ wv16) {
  const int y = blockIdx.y;
  const float* src; u16* dst; int n8;
  if (y == 0)      { src = q;  dst = q16;  n8 = (BB * SLQ * AHD) / 8; }
  else if (y == 1) { src = k;  dst = k16;  n8 = (BB * SLK * AHD) / 8; }
  else if (y == 2) { src = wq; dst = wq16; n8 = (AHD * DIM) / 8; }
  else if (y == 3) { src = wk; dst = wk16; n8 = (AHD * DIM) / 8; }
  else             { src = wv; dst = wv16; n8 = (AHD * DIM) / 8; }
  for (int i = blockIdx.x * 256 + threadIdx.x; i < n8; i += 512 * 256) {
    float4 a = ((const float4*)src)[i * 2];
    float4 b = ((const float4*)src)[i * 2 + 1];
    F8 c;
    c.v = (f16x8){(_Float16)a.x, (_Float16)a.y, (_Float16)a.z, (_Float16)a.w,
                  (_Float16)b.x, (_Float16)b.y, (_Float16)b.z, (_Float16)b.w};
    ((uint4*)dst)[i] = c.u4;
  }
}

// ---------------- fused fp16-MFMA projections: z=0 Q, z=1 K, z=2 V(transposed out) ----------------
__global__ __launch_bounds__(256) void proj_mfma(
    const u16* __restrict__ X16q, const u16* __restrict__ X16k,
    const u16* __restrict__ Wq16, const u16* __restrict__ Wk16, const u16* __restrict__ Wv16,
    const float* __restrict__ bq, const float* __restrict__ bk, const float* __restrict__ bv,
    u16* __restrict__ Qb, u16* __restrict__ Kb, u16* __restrict__ Vtb) {
  __shared__ __align__(16) u16 As[128 * 32];
  __shared__ __align__(16) u16 Bs[128 * 32];
  const int t  = threadIdx.x;
  const int w  = t >> 6, l = t & 63;
  const int lr = l & 15, lg = l >> 4;
  const int wr = w >> 1, wc = w & 1;
  const int bm = blockIdx.x * 128, bn = blockIdx.y * 128;
  const int z  = blockIdx.z;

  const u16*   Xs = (z == 0) ? X16q : X16k;
  const u16*   Ws = (z == 0) ? Wq16 : (z == 1 ? Wk16 : Wv16);
  const float* bs = (z == 0) ? bq   : (z == 1 ? bk   : bv);
  u16* Y  = (z == 0) ? Qb : (z == 1 ? Kb : nullptr);
  u16* Yt = (z == 2) ? Vtb : nullptr;

  const int srow = t >> 1;
  const int half = t & 1;

  f32x4 acc[4][4];
#pragma unroll
  for (int i = 0; i < 4; ++i)
#pragma unroll
    for (int j = 0; j < 4; ++j) acc[i][j] = (f32x4){0.f, 0.f, 0.f, 0.f};

  for (int k0 = 0; k0 < DIM; k0 += 32) {
    __syncthreads();
    {
      const u16* src = Xs + (size_t)(bm + srow) * DIM + k0 + half * 16;
      uint4 g0 = ((const uint4*)src)[0];
      uint4 g1 = ((const uint4*)src)[1];
      *(uint4*)&As[srow * 32 + ((half * 2)     ^ (srow & 3)) * 8] = g0;
      *(uint4*)&As[srow * 32 + ((half * 2 + 1) ^ (srow & 3)) * 8] = g1;
    }
    {
      const u16* src = Ws + (size_t)(bn + srow) * DIM + k0 + half * 16;
      uint4 g0 = ((const uint4*)src)[0];
      uint4 g1 = ((const uint4*)src)[1];
      *(uint4*)&Bs[srow * 32 + ((half * 2)     ^ (srow & 3)) * 8] = g0;
      *(uint4*)&Bs[srow * 32 + ((half * 2 + 1) ^ (srow & 3)) * 8] = g1;
    }
    __syncthreads();

    f16x8 af[4], bf[4];
#pragma unroll
    for (int mt = 0; mt < 4; ++mt) {
      const int row = wr * 64 + mt * 16 + lr;
      af[mt] = ldsF8(&As[row * 32 + (lg ^ (row & 3)) * 8]);
    }
#pragma unroll
    for (int nt = 0; nt < 4; ++nt) {
      const int row = wc * 64 + nt * 16 + lr;
      bf[nt] = ldsF8(&Bs[row * 32 + (lg ^ (row & 3)) * 8]);
    }
    __builtin_amdgcn_s_setprio(1);
#pragma unroll
    for (int mt = 0; mt < 4; ++mt)
#pragma unroll
      for (int nt = 0; nt < 4; ++nt)
        acc[mt][nt] = __builtin_amdgcn_mfma_f32_16x16x32_f16(af[mt], bf[nt], acc[mt][nt], 0, 0, 0);
    __builtin_amdgcn_s_setprio(0);
  }

  float bvn[4];
#pragma unroll
  for (int nt = 0; nt < 4; ++nt) bvn[nt] = bs[bn + wc * 64 + nt * 16 + lr];

#pragma unroll
  for (int mt = 0; mt < 4; ++mt) {
    const int m0 = bm + wr * 64 + mt * 16 + lg * 4;
#pragma unroll
    for (int nt = 0; nt < 4; ++nt) {
      const int n = bn + wc * 64 + nt * 16 + lr;
#pragma unroll
      for (int r = 0; r < 4; ++r) {
        const float val = acc[mt][nt][r] + bvn[nt];
        const u16 hv = f2h(val);
        const int m = m0 + r;
        if (Y)  Y[(size_t)m * DIM + n] = hv;
        if (Yt) {
          const int b2 = m >> 10, ll = m & 1023;
          Yt[((size_t)b2 * DIM + n) * SLK + ll] = hv;
        }
      }
    }
  }
}

// ---------------- swapped-QK^T MFMA attention pass ----------------
template <bool DO_PV, bool NORM_P, bool ACC_L>
__device__ __forceinline__ void attn_pass(
    const u16* __restrict__ Kg, const u16* __restrict__ Vg,
    const float* __restrict__ Msf,
    u16* __restrict__ Ks0, u16* __restrict__ Ks1,
    u16* __restrict__ Vs0, u16* __restrict__ Vs1,
    u16* __restrict__ Psw,
    const f16x8 (&qa)[2][2], const int lr, const int lg,
    float (&lrun)[2], const float (&invl)[2], f32x4 (&oacc)[2][4],
    float* __restrict__ Pout, const size_t poutRow0,
    const int skey, const int sj) {
  const float scale = 0.03608439182435161f;  // 1/sqrt(768)

  // prologue: stage tile 0
  {
    const u16* s = Kg + (size_t)skey * AHD + sj * 8;
    uint4 a = ((const uint4*)s)[0], b2 = ((const uint4*)s)[1];
    *(uint4*)&Ks0[skey * 64 + ((sj)     ^ (skey & 7)) * 8] = a;
    *(uint4*)&Ks0[skey * 64 + ((sj + 1) ^ (skey & 7)) * 8] = b2;
    if (DO_PV) {
      const u16* sv = Vg + (size_t)skey * SLK + sj * 8;
      uint4 va = ((const uint4*)sv)[0], vb = ((const uint4*)sv)[1];
      *(uint4*)&Vs0[skey * 64 + ((sj)     ^ (skey & 7)) * 8] = va;
      *(uint4*)&Vs0[skey * 64 + ((sj + 1) ^ (skey & 7)) * 8] = vb;
    }
  }
  __syncthreads();

#pragma unroll 2
  for (int kt = 0; kt < SLK / 64; ++kt) {
    const int k0 = kt * 64;
    u16* Kc = (kt & 1) ? Ks1 : Ks0;
    u16* Kn = (kt & 1) ? Ks0 : Ks1;
    u16* Vc = (kt & 1) ? Vs1 : Vs0;
    u16* Vn = (kt & 1) ? Vs0 : Vs1;
    const bool more = (kt < SLK / 64 - 1);

    // T14: issue next-tile loads now, write to LDS after compute
    uint4 ka = {}, kb2 = {}, va = {}, vb = {};
    if (more) {
      const u16* s = Kg + (size_t)(k0 + 64 + skey) * AHD + sj * 8;
      ka = ((const uint4*)s)[0]; kb2 = ((const uint4*)s)[1];
      if (DO_PV) {
        const u16* sv = Vg + (size_t)skey * SLK + (k0 + 64) + sj * 8;
        va = ((const uint4*)sv)[0]; vb = ((const uint4*)sv)[1];
      }
    }

    // QK^T (swapped): 16 MFMA
    f32x4 sacc[2][4];
#pragma unroll
    for (int mt = 0; mt < 2; ++mt)
#pragma unroll
      for (int ct = 0; ct < 4; ++ct) sacc[mt][ct] = (f32x4){0.f, 0.f, 0.f, 0.f};
    __builtin_amdgcn_s_setprio(1);
#pragma unroll
    for (int ct = 0; ct < 4; ++ct) {
      const int krow = ct * 16 + lr;
      f16x8 kf0 = ldsF8(&Kc[krow * 64 + ((lg)     ^ (krow & 7)) * 8]);
      f16x8 kf1 = ldsF8(&Kc[krow * 64 + ((4 + lg) ^ (krow & 7)) * 8]);
      sacc[0][ct] = __builtin_amdgcn_mfma_f32_16x16x32_f16(kf0, qa[0][0], sacc[0][ct], 0, 0, 0);
      sacc[0][ct] = __builtin_amdgcn_mfma_f32_16x16x32_f16(kf1, qa[0][1], sacc[0][ct], 0, 0, 0);
      sacc[1][ct] = __builtin_amdgcn_mfma_f32_16x16x32_f16(kf0, qa[1][0], sacc[1][ct], 0, 0, 0);
      sacc[1][ct] = __builtin_amdgcn_mfma_f32_16x16x32_f16(kf1, qa[1][1], sacc[1][ct], 0, 0, 0);
    }
    __builtin_amdgcn_s_setprio(0);

    // softmax numerators (p overwrites sacc); mask multiplicative from LDS
    float ps[2] = {0.f, 0.f};
#pragma unroll
    for (int ct = 0; ct < 4; ++ct) {
      const float4 mm = *(const float4*)&Msf[k0 + ct * 16 + lg * 4];
      const float m4[4] = {mm.x, mm.y, mm.z, mm.w};
#pragma unroll
      for (int mt = 0; mt < 2; ++mt)
#pragma unroll
        for (int r = 0; r < 4; ++r) {
          float p = __expf(sacc[mt][ct][r] * scale) * m4[r];
          if (NORM_P) p *= invl[mt];
          sacc[mt][ct][r] = p;
          if (ACC_L) ps[mt] += p;
        }
    }
    if (ACC_L) {
#pragma unroll
      for (int mt = 0; mt < 2; ++mt) {
        float s = ps[mt];
        s += __shfl_xor(s, 16);
        s += __shfl_xor(s, 32);
        lrun[mt] += s;
      }
    }

    if (NORM_P) {
      // p2 write: contiguous float4 along k per (mt,ct)
#pragma unroll
      for (int mt = 0; mt < 2; ++mt)
#pragma unroll
        for (int ct = 0; ct < 4; ++ct) {
          float4 pv = make_float4(sacc[mt][ct][0], sacc[mt][ct][1], sacc[mt][ct][2], sacc[mt][ct][3]);
          *(float4*)&Pout[(poutRow0 + mt * 16 + lr) * (size_t)SLK + k0 + ct * 16 + lg * 4] = pv;
        }
    }

    if (DO_PV) {
      // packed P -> LDS: 8x ds_write_b64
#pragma unroll
      for (int mt = 0; mt < 2; ++mt) {
        const int prow = mt * 16 + lr;
#pragma unroll
        for (int ct = 0; ct < 4; ++ct) {
          uint2 w2;
          w2.x = pk2(sacc[mt][ct][0], sacc[mt][ct][1]);
          w2.y = pk2(sacc[mt][ct][2], sacc[mt][ct][3]);
          *(uint2*)&Psw[prow * 64 + (((ct * 2 + (lg >> 1)) ^ (prow & 7)) * 8) + (lg & 1) * 4] = w2;
        }
      }
      // preload V fragments (independent of P writes) — hides P-write latency
      f16x8 vf[4][2];
#pragma unroll
      for (int dt = 0; dt < 4; ++dt) {
        const int vrow = dt * 16 + lr;
        vf[dt][0] = ldsF8(&Vc[vrow * 64 + ((lg)     ^ (vrow & 7)) * 8]);
        vf[dt][1] = ldsF8(&Vc[vrow * 64 + ((4 + lg) ^ (vrow & 7)) * 8]);
      }
      __asm__ volatile("s_waitcnt lgkmcnt(0)" ::: "memory");
      __builtin_amdgcn_sched_barrier(0);

      f16x8 pa[2][2];
#pragma unroll
      for (int mt = 0; mt < 2; ++mt) {
        const int prow = mt * 16 + lr;
        pa[mt][0] = ldsF8(&Psw[prow * 64 + ((lg)     ^ (prow & 7)) * 8]);
        pa[mt][1] = ldsF8(&Psw[prow * 64 + ((4 + lg) ^ (prow & 7)) * 8]);
      }
      __builtin_amdgcn_s_setprio(1);
#pragma unroll
      for (int dt = 0; dt < 4; ++dt) {
        oacc[0][dt] = __builtin_amdgcn_mfma_f32_16x16x32_f16(pa[0][0], vf[dt][0], oacc[0][dt], 0, 0, 0);
        oacc[0][dt] = __builtin_amdgcn_mfma_f32_16x16x32_f16(pa[0][1], vf[dt][1], oacc[0][dt], 0, 0, 0);
        oacc[1][dt] = __builtin_amdgcn_mfma_f32_16x16x32_f16(pa[1][0], vf[dt][0], oacc[1][dt], 0, 0, 0);
        oacc[1][dt] = __builtin_amdgcn_mfma_f32_16x16x32_f16(pa[1][1], vf[dt][1], oacc[1][dt], 0, 0, 0);
      }
      __builtin_amdgcn_s_setprio(0);
    }

    // late LDS write of prefetched tile
    if (more) {
      *(uint4*)&Kn[skey * 64 + ((sj)     ^ (skey & 7)) * 8] = ka;
      *(uint4*)&Kn[skey * 64 + ((sj + 1) ^ (skey & 7)) * 8] = kb2;
      if (DO_PV) {
        *(uint4*)&Vn[skey * 64 + ((sj)     ^ (skey & 7)) * 8] = va;
        *(uint4*)&Vn[skey * 64 + ((sj + 1) ^ (skey & 7)) * 8] = vb;
      }
    }
    __syncthreads();
  }
}

// MODE 0: stage 1 — single pass, unnormalized PV + denom, writes O fp16 + O^T fp16.
// MODE 1: stage 2 — pass1 (denoms), pass2 (normalized p2 f32 + PV), writes tanh f32.
template <int MODE>
__global__ __launch_bounds__(256) void attn_mfma(
    const u16* __restrict__ Qm, const u16* __restrict__ Km,
    const u16* __restrict__ Vt, const int* __restrict__ mask,
    u16* __restrict__ O16, u16* __restrict__ O16t,
    float* __restrict__ Of32, float* __restrict__ Pout) {
  __shared__ __align__(16) u16 Ks[2][64 * 64];
  __shared__ __align__(16) u16 Vs[2][64 * 64];
  __shared__ __align__(16) u16 Ps[4][32 * 64];
  __shared__ __align__(16) float Msf[SLK];

  const int t  = threadIdx.x;
  const int w  = t >> 6, l = t & 63;
  const int lr = l & 15, lg = l >> 4;
  const int b  = blockIdx.y, h = blockIdx.z;
  const int qr0 = blockIdx.x * 128 + w * 32;

  // mask -> LDS as float 0/1 (visible after attn_pass's prologue barrier)
  {
    const int4 mi = ((const int4*)(mask + (size_t)b * SLK))[t];
    *(float4*)&Msf[t * 4] = make_float4(mi.x == 1 ? 1.f : 0.f, mi.y == 1 ? 1.f : 0.f,
                                        mi.z == 1 ? 1.f : 0.f, mi.w == 1 ? 1.f : 0.f);
  }

  // Q fragments (held across passes)
  f16x8 qa[2][2];
#pragma unroll
  for (int mt = 0; mt < 2; ++mt) {
    const u16* qp = Qm + (size_t)(b * SLQ + qr0 + mt * 16 + lr) * AHD + h * DH + lg * 8;
    qa[mt][0] = *(const f16x8*)qp;
    qa[mt][1] = *(const f16x8*)(qp + 32);
  }

  const u16* Kg = Km + (size_t)b * SLK * AHD + h * DH;
  const u16* Vg = Vt + ((size_t)b * AHD + h * DH) * SLK;
  const size_t poutRow0 = ((size_t)(h * BB + b)) * SLQ + qr0;
  const int skey = t >> 2, sj = (t & 3) * 2;

  float lrun[2] = {0.f, 0.f};
  float invl[2] = {1.f, 1.f};
  f32x4 oacc[2][4];
#pragma unroll
  for (int mt = 0; mt < 2; ++mt)
#pragma unroll
    for (int dt = 0; dt < 4; ++dt) oacc[mt][dt] = (f32x4){0.f, 0.f, 0.f, 0.f};

  if (MODE == 0) {
    attn_pass<true, false, true>(Kg, Vg, Msf, Ks[0], Ks[1], Vs[0], Vs[1], Ps[w],
                                 qa, lr, lg, lrun, invl, oacc, nullptr, 0, skey, sj);
#pragma unroll
    for (int mt = 0; mt < 2; ++mt) invl[mt] = 1.f / lrun[mt];
#pragma unroll
    for (int mt = 0; mt < 2; ++mt) {
      float iv[4];
#pragma unroll
      for (int r = 0; r < 4; ++r) iv[r] = __shfl(invl[mt], lg * 4 + r);
#pragma unroll
      for (int dt = 0; dt < 4; ++dt) {
        const int d = h * DH + dt * 16 + lr;
#pragma unroll
        for (int r = 0; r < 4; ++r) {
          const int q = qr0 + mt * 16 + lg * 4 + r;
          const u16 hv = f2h(oacc[mt][dt][r] * iv[r]);
          O16[(size_t)(b * SLQ + q) * AHD + d] = hv;
          O16t[((size_t)b * AHD + d) * SLQ + q] = hv;
        }
      }
    }
  } else {
    attn_pass<false, false, true>(Kg, Vg, Msf, Ks[0], Ks[1], Vs[0], Vs[1], Ps[w],
                                  qa, lr, lg, lrun, invl, oacc, nullptr, 0, skey, sj);
#pragma unroll
    for (int mt = 0; mt < 2; ++mt) invl[mt] = 1.f / lrun[mt];
    attn_pass<true, true, false>(Kg, Vg, Msf, Ks[0], Ks[1], Vs[0], Vs[1], Ps[w],
                                 qa, lr, lg, lrun, invl, oacc, Pout, poutRow0, skey, sj);
#pragma unroll
    for (int mt = 0; mt < 2; ++mt)
#pragma unroll
      for (int dt = 0; dt < 4; ++dt) {
        const int d = h * DH + dt * 16 + lr;
#pragma unroll
        for (int r = 0; r < 4; ++r) {
          const int q = qr0 + mt * 16 + lg * 4 + r;
          Of32[(size_t)(b * SLQ + q) * AHD + d] = tanhf(oacc[mt][dt][r]);
        }
      }
  }
}

extern "C" void kernel_launch(void* const* d_in, const int* in_sizes, int n_in,
                              void* d_out, int out_size, void* d_ws, size_t ws_size,
                              hipStream_t stream) {
  const float* query = (const float*)d_in[0];
  const float* key   = (const float*)d_in[1];
  const int*   qmask = (const int*)d_in[2];
  const int*   kmask = (const int*)d_in[3];
  const float* Wq = (const float*)d_in[4];
  const float* bq = (const float*)d_in[5];
  const float* Wk = (const float*)d_in[6];
  const float* bk = (const float*)d_in[7];
  const float* Wv = (const float*)d_in[8];
  const float* bv = (const float*)d_in[9];

  float* out = (float*)d_out;
  const size_t bufE = (size_t)BB * SLQ * AHD;  // 6,291,456
  const size_t wE   = (size_t)AHD * DIM;       // 589,824
  float* p2out = out + bufE;                   // [H,B,LQ,LK] region (402 MB)

  // fp16 scratch in the not-yet-written p2 region (all dead before stage-2 writes p2):
  u16* Qb   = (u16*)p2out;
  u16* Kb   = Qb + bufE;
  u16* Vtb  = Kb + bufE;       // V^T [B,768,1024]
  u16* q16  = Vtb + bufE;
  u16* k16  = q16 + bufE;
  u16* wq16 = k16 + bufE;
  u16* wk16 = wq16 + wE;
  u16* wv16 = wk16 + wE;
  // O1 / O1^T in d_ws (read by stage 2 while p2 is written):
  u16* O1  = (u16*)d_ws;
  u16* O1t = O1 + bufE;

  cvt_f16<<<dim3(512, 5), dim3(256), 0, stream>>>(query, key, Wq, Wk, Wv,
                                                  q16, k16, wq16, wk16, wv16);

  dim3 pgrid(8192 / 128, DIM / 128, 3);  // (64, 6, 3) = 1152 blocks, 4.5/CU
  proj_mfma<<<pgrid, dim3(256), 0, stream>>>(q16, k16, wq16, wk16, wv16,
                                             bq, bk, bv, Qb, Kb, Vtb);

  dim3 agrid(SLQ / 128, BB, NH);  // (8, 8, 12) = 768 blocks, 3/CU
  attn_mfma<0><<<agrid, dim3(256), 0, stream>>>(Qb, Kb, Vtb, kmask, O1, O1t, nullptr, nullptr);
  attn_mfma<1><<<agrid, dim3(256), 0, stream>>>(O1, O1, O1t, qmask, nullptr, nullptr, out, p2out);
}